// Round 1
// baseline (445.697 us; speedup 1.0000x reference)
//
#include <hip/hip_runtime.h>

#define DEVI __device__ __forceinline__

typedef short bf16x8 __attribute__((ext_vector_type(8)));
typedef float f32x4 __attribute__((ext_vector_type(4)));
typedef unsigned short u16;
typedef unsigned int u32;

// Problem constants
static constexpr int Bn = 2, S = 2048, E = 1024, H = 16, D = 64;
static constexpr int Mrows = Bn * S;          // 4096
static constexpr int N_QKV = 3 * E;           // 3072

DEVI u16 f2b(float f) {
  union { float f; u32 u; } c; c.f = f;
  return (u16)((c.u + 0x7FFFu + ((c.u >> 16) & 1u)) >> 16);
}

DEVI bf16x8 ld8(const u16* p) {
  union { uint4 u; bf16x8 v; } c;
  c.u = *reinterpret_cast<const uint4*>(p);
  return c.v;
}

#define MFMA(a, b, c) __builtin_amdgcn_mfma_f32_16x16x32_bf16(a, b, c, 0, 0, 0)

// ---------------- fp32 -> bf16 elementwise (x) ----------------
__global__ void conv_bf16(const float* __restrict__ in, u16* __restrict__ out, int n4) {
  int i = blockIdx.x * blockDim.x + threadIdx.x;
  if (i < n4) {
    float4 f = reinterpret_cast<const float4*>(in)[i];
    ushort4 u;
    u.x = f2b(f.x); u.y = f2b(f.y); u.z = f2b(f.z); u.w = f2b(f.w);
    reinterpret_cast<ushort4*>(out)[i] = u;
  }
}

// ---------------- fp32 [R][C] -> bf16 [C][R] transpose (weights) ----------------
__global__ void transpose_bf16(const float* __restrict__ in, u16* __restrict__ out, int R, int C) {
  __shared__ float t[32][33];
  int bx = blockIdx.x * 32;  // C
  int by = blockIdx.y * 32;  // R
  int tx = threadIdx.x, ty = threadIdx.y;
#pragma unroll
  for (int k = 0; k < 32; k += 8)
    t[ty + k][tx] = in[(size_t)(by + ty + k) * C + bx + tx];
  __syncthreads();
#pragma unroll
  for (int k = 0; k < 32; k += 8)
    out[(size_t)(bx + ty + k) * R + by + tx] = f2b(t[tx][ty + k]);
}

// ---------------- GEMM1: qkv = xb[4096,1024] @ wabT[3072,1024]^T ----------------
// Epilogue scatters into Q (scaled 1/8) [B,H,S,D], K [B,H,S,D], V^T [B,H,D,S], bf16.
__global__ __launch_bounds__(256) void gemm_qkv(const u16* __restrict__ A, const u16* __restrict__ BT,
                                                u16* __restrict__ Qb, u16* __restrict__ Kb,
                                                u16* __restrict__ VbT) {
  const int K = E;
  int w = threadIdx.x >> 6, lane = threadIdx.x & 63, quad = lane >> 4, l15 = lane & 15;
  int mbase = blockIdx.x * 128 + (w >> 1) * 64;
  int nbase = blockIdx.y * 128 + (w & 1) * 64;
  f32x4 acc[4][4] = {};
  const u16* pA = A + (size_t)(mbase + l15) * K + quad * 8;
  const u16* pB = BT + (size_t)(nbase + l15) * K + quad * 8;
  for (int k0 = 0; k0 < K; k0 += 32) {
    bf16x8 a[4], b[4];
#pragma unroll
    for (int i = 0; i < 4; i++) a[i] = ld8(pA + (size_t)i * 16 * K + k0);
#pragma unroll
    for (int i = 0; i < 4; i++) b[i] = ld8(pB + (size_t)i * 16 * K + k0);
#pragma unroll
    for (int mb = 0; mb < 4; mb++)
#pragma unroll
      for (int nb = 0; nb < 4; nb++)
        acc[mb][nb] = MFMA(a[mb], b[nb], acc[mb][nb]);
  }
#pragma unroll
  for (int mb = 0; mb < 4; mb++) {
    int m0 = mbase + mb * 16 + quad * 4;       // rows m0..m0+3 (same batch: tiles never straddle)
    int b = m0 >> 11, s = m0 & 2047;
#pragma unroll
    for (int nb = 0; nb < 4; nb++) {
      int n = nbase + nb * 16 + l15;
      int sec = n >> 10, e = n & 1023, h = e >> 6, d = e & 63;
      int bh = b * H + h;
      if (sec == 0) {
#pragma unroll
        for (int r = 0; r < 4; r++)
          Qb[((size_t)bh * S + s + r) * D + d] = f2b(acc[mb][nb][r] * 0.125f);
      } else if (sec == 1) {
#pragma unroll
        for (int r = 0; r < 4; r++)
          Kb[((size_t)bh * S + s + r) * D + d] = f2b(acc[mb][nb][r]);
      } else {
        ushort4 v;
        v.x = f2b(acc[mb][nb][0]); v.y = f2b(acc[mb][nb][1]);
        v.z = f2b(acc[mb][nb][2]); v.w = f2b(acc[mb][nb][3]);
        *reinterpret_cast<ushort4*>(VbT + ((size_t)bh * D + d) * S + s) = v;
      }
    }
  }
}

// ---------------- Flash attention: per-(b,h,qtile64) block, 4 waves x 16 q-rows ----------------
__global__ __launch_bounds__(256) void attn(const u16* __restrict__ Qb, const u16* __restrict__ Kb,
                                            const u16* __restrict__ VbT, u16* __restrict__ Yb) {
  __shared__ __align__(16) u16 P[4][16][72];   // per-wave private P tile, row stride 144B (16B-aligned)
  int w = threadIdx.x >> 6, lane = threadIdx.x & 63, quad = lane >> 4, l15 = lane & 15;
  int qt = blockIdx.x & 31, bh = blockIdx.x >> 5;
  int b = bh >> 4, h = bh & 15;
  int q_base = qt * 64 + w * 16;

  const u16* Qp = Qb + ((size_t)bh * S + q_base + l15) * D + quad * 8;
  bf16x8 aq0 = ld8(Qp), aq1 = ld8(Qp + 32);

  float m_i[4], l_i[4];
  f32x4 o[4] = {};
#pragma unroll
  for (int r = 0; r < 4; r++) { m_i[r] = -1e30f; l_i[r] = 0.f; }

  for (int kt = 0; kt <= qt; kt++) {
    int kbase = kt * 64;
    f32x4 sc[4] = {};
    const u16* Kp = Kb + ((size_t)bh * S + kbase + l15) * D + quad * 8;
#pragma unroll
    for (int nb = 0; nb < 4; nb++) {
      bf16x8 bk0 = ld8(Kp + (size_t)nb * 16 * D);
      bf16x8 bk1 = ld8(Kp + (size_t)nb * 16 * D + 32);
      sc[nb] = MFMA(aq0, bk0, sc[nb]);
      sc[nb] = MFMA(aq1, bk1, sc[nb]);
    }
    if (kt == qt) {  // diagonal tile: causal mask
#pragma unroll
      for (int nb = 0; nb < 4; nb++) {
        int key = kbase + nb * 16 + l15;
#pragma unroll
        for (int r = 0; r < 4; r++) {
          int qrow = q_base + quad * 4 + r;
          if (key > qrow) sc[nb][r] = -1e30f;
        }
      }
    }
    // online softmax (rows live in reg r, replicated across the 16 lanes of each quad)
    float mloc[4], psum[4], alpha[4];
#pragma unroll
    for (int r = 0; r < 4; r++)
      mloc[r] = fmaxf(fmaxf(sc[0][r], sc[1][r]), fmaxf(sc[2][r], sc[3][r]));
#pragma unroll
    for (int off = 8; off >= 1; off >>= 1)
#pragma unroll
      for (int r = 0; r < 4; r++) mloc[r] = fmaxf(mloc[r], __shfl_xor(mloc[r], off, 64));
#pragma unroll
    for (int r = 0; r < 4; r++) {
      float mn = fmaxf(m_i[r], mloc[r]);
      alpha[r] = __expf(m_i[r] - mn);
      m_i[r] = mn;
      psum[r] = 0.f;
    }
#pragma unroll
    for (int nb = 0; nb < 4; nb++)
#pragma unroll
      for (int r = 0; r < 4; r++) {
        float p = __expf(sc[nb][r] - m_i[r]);
        psum[r] += p;
        P[w][quad * 4 + r][nb * 16 + l15] = f2b(p);
      }
#pragma unroll
    for (int off = 8; off >= 1; off >>= 1)
#pragma unroll
      for (int r = 0; r < 4; r++) psum[r] += __shfl_xor(psum[r], off, 64);
#pragma unroll
    for (int r = 0; r < 4; r++) l_i[r] = l_i[r] * alpha[r] + psum[r];
#pragma unroll
    for (int nb = 0; nb < 4; nb++)
#pragma unroll
      for (int r = 0; r < 4; r++) o[nb][r] *= alpha[r];
    __syncthreads();   // uniform trip count across all 4 waves (kt <= qt for every wave)
    bf16x8 ap0 = ld8(&P[w][l15][quad * 8]);
    bf16x8 ap1 = ld8(&P[w][l15][32 + quad * 8]);
    const u16* Vp = VbT + ((size_t)bh * D + l15) * S + kbase + quad * 8;
#pragma unroll
    for (int nb = 0; nb < 4; nb++) {
      bf16x8 bv0 = ld8(Vp + (size_t)nb * 16 * S);
      bf16x8 bv1 = ld8(Vp + (size_t)nb * 16 * S + 32);
      o[nb] = MFMA(ap0, bv0, o[nb]);
      o[nb] = MFMA(ap1, bv1, o[nb]);
    }
    __syncthreads();
  }
  // epilogue: Y[b][s][h*64+d] bf16
#pragma unroll
  for (int nb = 0; nb < 4; nb++)
#pragma unroll
    for (int r = 0; r < 4; r++) {
      float val = o[nb][r] / l_i[r];
      int m = q_base + quad * 4 + r;
      Yb[((size_t)b * S + m) * E + h * 64 + nb * 16 + l15] = f2b(val);
    }
}

// ---------------- GEMM2: out = Yb[4096,1024] @ wpbT[1024,1024]^T, fp32 out ----------------
__global__ __launch_bounds__(256) void gemm_proj(const u16* __restrict__ A, const u16* __restrict__ BT,
                                                 float* __restrict__ out) {
  const int K = E;
  int w = threadIdx.x >> 6, lane = threadIdx.x & 63, quad = lane >> 4, l15 = lane & 15;
  int mbase = blockIdx.x * 128 + (w >> 1) * 64;
  int nbase = blockIdx.y * 128 + (w & 1) * 64;
  f32x4 acc[4][4] = {};
  const u16* pA = A + (size_t)(mbase + l15) * K + quad * 8;
  const u16* pB = BT + (size_t)(nbase + l15) * K + quad * 8;
  for (int k0 = 0; k0 < K; k0 += 32) {
    bf16x8 a[4], b[4];
#pragma unroll
    for (int i = 0; i < 4; i++) a[i] = ld8(pA + (size_t)i * 16 * K + k0);
#pragma unroll
    for (int i = 0; i < 4; i++) b[i] = ld8(pB + (size_t)i * 16 * K + k0);
#pragma unroll
    for (int mb = 0; mb < 4; mb++)
#pragma unroll
      for (int nb = 0; nb < 4; nb++)
        acc[mb][nb] = MFMA(a[mb], b[nb], acc[mb][nb]);
  }
#pragma unroll
  for (int mb = 0; mb < 4; mb++) {
    int m0 = mbase + mb * 16 + quad * 4;
#pragma unroll
    for (int nb = 0; nb < 4; nb++) {
      int n = nbase + nb * 16 + l15;
#pragma unroll
      for (int r = 0; r < 4; r++)
        out[(size_t)(m0 + r) * E + n] = acc[mb][nb][r];
    }
  }
}

extern "C" void kernel_launch(void* const* d_in, const int* in_sizes, int n_in,
                              void* d_out, int out_size, void* d_ws, size_t ws_size,
                              hipStream_t stream) {
  const float* x = (const float*)d_in[0];
  const float* w_attn = (const float*)d_in[1];
  const float* w_proj = (const float*)d_in[2];
  float* out = (float*)d_out;
  char* ws = (char*)d_ws;

  // workspace layout (bytes)
  u16* xb   = (u16*)(ws);                      // 4096*1024*2 = 8 MB
  u16* wabT = (u16*)(ws + 8388608);            // 3072*1024*2 = 6 MB
  u16* wpbT = (u16*)(ws + 14680064);           // 1024*1024*2 = 2 MB
  u16* Qb   = (u16*)(ws + 16777216);           // 8 MB
  u16* Kb   = (u16*)(ws + 25165824);           // 8 MB
  u16* VbT  = (u16*)(ws + 33554432);           // 8 MB
  u16* Yb   = (u16*)(ws + 41943040);           // 8 MB   (total 48 MB)

  conv_bf16<<<4096, 256, 0, stream>>>(x, xb, Mrows * E / 4);
  transpose_bf16<<<dim3(N_QKV / 32, E / 32), dim3(32, 8), 0, stream>>>(w_attn, wabT, E, N_QKV);
  transpose_bf16<<<dim3(E / 32, E / 32), dim3(32, 8), 0, stream>>>(w_proj, wpbT, E, E);
  gemm_qkv<<<dim3(Mrows / 128, N_QKV / 128), 256, 0, stream>>>(xb, wabT, Qb, Kb, VbT);
  attn<<<Bn * H * (S / 64), 256, 0, stream>>>(Qb, Kb, VbT, Yb);
  gemm_proj<<<dim3(Mrows / 128, E / 128), 256, 0, stream>>>(Yb, wpbT, out);
}